// Round 10
// baseline (15508.052 us; speedup 1.0000x reference)
//
#include <hip/hip_runtime.h>
#include <stdint.h>
#include <stddef.h>

#define HH 256
#define WW 256
#define NCH 20
#define KH 128
#define TSX 16
#define TSY 16

// JAX threefry2x32 (20 rounds), exact.
__host__ __device__ inline void tf2x32(uint32_t k0, uint32_t k1,
                                       uint32_t x0, uint32_t x1,
                                       uint32_t* o0, uint32_t* o1) {
  uint32_t ks0 = k0, ks1 = k1, ks2 = k0 ^ k1 ^ 0x1BD11BDAu;
  x0 += ks0; x1 += ks1;
#define RND(r) { x0 += x1; x1 = (x1 << (r)) | (x1 >> (32 - (r))); x1 ^= x0; }
  RND(13) RND(15) RND(26) RND(6)   x0 += ks1; x1 += ks2 + 1u;
  RND(17) RND(29) RND(16) RND(24)  x0 += ks2; x1 += ks0 + 2u;
  RND(13) RND(15) RND(26) RND(6)   x0 += ks0; x1 += ks1 + 3u;
  RND(17) RND(29) RND(16) RND(24)  x0 += ks1; x1 += ks2 + 4u;
  RND(13) RND(15) RND(26) RND(6)   x0 += ks2; x1 += ks0 + 5u;
#undef RND
  *o0 = x0; *o1 = x1;
}

__device__ inline float fire_of(uint32_t fk0, uint32_t fk1, uint32_t f) {
  // JAX partitionable threefry: counts hi=0, lo=f; bits = o0 ^ o1
  uint32_t o0, o1;
  tf2x32(fk0, fk1, 0u, f, &o0, &o1);
  uint32_t bits = o0 ^ o1;
  float u = __uint_as_float((bits >> 9) | 0x3f800000u) - 1.0f;
  return (u < 0.5f) ? 1.0f : 0.0f;
}

// One NCA step, ONE pixel per thread: live set p[60]+dx[17]+acc ~95 regs
// -> fits the 128 arch-VGPR allocation with zero AGPR/scratch spill
// (r6/r8 lesson: 2px/thread live set ~154 forced accvgpr churn ~= +108% VALU issue).
// W1 in LDS (uniform broadcast ds_read_b128, parallel pipe); W2/b1 s_load (K$-hot).
__global__ __attribute__((amdgpu_flat_work_group_size(256, 256), amdgpu_waves_per_eu(2, 2)))
void nca_step(
    const float* __restrict__ xin, float* __restrict__ xout,
    const float* __restrict__ W1, const float* __restrict__ b1,
    const float* __restrict__ W2, uint32_t fk0, uint32_t fk1)
{
  __shared__ float xs[NCH][18][18];   // 25.92 KB halo tile (16x16 px + 1 halo)
  __shared__ float w1s[KH * 60];      // 30.72 KB; row k at 240B offset (16B aligned)

  const int tid = threadIdx.x;
  const int bx = blockIdx.x, by = blockIdx.y, bb = blockIdx.z;
  const int x0t = bx * TSX, y0t = by * TSY;
  const float* xb = xin + (size_t)bb * (NCH * HH * WW);

  // ---- stage W1 into LDS (float4 coalesced; 1920 float4s) ----
  for (int i = tid; i < KH * 15; i += 256)
    ((float4*)w1s)[i] = ((const float4*)W1)[i];

  // ---- stage halo tile (reflect padding) ----
  for (int idx = tid; idx < NCH * 18 * 18; idx += 256) {
    int c  = idx / 324;
    int r  = idx - c * 324;
    int ly = r / 18;
    int lx = r - ly * 18;
    int gy = y0t + ly - 1;
    int gx = x0t + lx - 1;
    gy = (gy < 0) ? -gy : gy;  gy = (gy >= HH) ? (2 * HH - 2 - gy) : gy;
    gx = (gx < 0) ? -gx : gx;  gx = (gx >= WW) ? (2 * WW - 2 - gx) : gx;
    xs[c][ly][lx] = xb[c * (HH * WW) + gy * WW + gx];
  }
  __syncthreads();

  const int tx = tid & 15, ty = tid >> 4;

  // ---- perceive: p[0..19]=center, p[20+2c]=sobel_x, p[21+2c]=sobel_y ----
  float p[60];
#pragma unroll
  for (int c = 0; c < NCH; ++c) {
    float a00 = xs[c][ty    ][tx], a01 = xs[c][ty    ][tx + 1], a02 = xs[c][ty    ][tx + 2];
    float a10 = xs[c][ty + 1][tx], a11 = xs[c][ty + 1][tx + 1], a12 = xs[c][ty + 1][tx + 2];
    float a20 = xs[c][ty + 2][tx], a21 = xs[c][ty + 2][tx + 1], a22 = xs[c][ty + 2][tx + 2];
    p[c] = a11;
    p[NCH + 2 * c    ] = ((a02 - a00) + 2.f * (a12 - a10) + (a22 - a20)) * 0.125f;
    p[NCH + 2 * c + 1] = ((a20 - a00) + 2.f * (a21 - a01) + (a22 - a02)) * 0.125f;
  }

  // dx only for mutable channels 3..19 (0..2 discarded by chan_mask)
  float dx[17];
#pragma unroll
  for (int c = 0; c < 17; ++c) dx[c] = 0.f;

  // ---- fused MLP over 128 hidden units ----
#pragma unroll 1
  for (int k = 0; k < KH; ++k) {
    const float bk = b1[k];              // s_load, 512B -> K$-hot
    float a0 = bk, a1 = 0.f, a2 = 0.f, a3 = 0.f;
#pragma unroll
    for (int c = 0; c < 60; c += 4) {
      float4 w = *(const float4*)&w1s[k * 60 + c];   // uniform broadcast ds_read_b128
      a0 = fmaf(w.x, p[c    ], a0);
      a1 = fmaf(w.y, p[c + 1], a1);
      a2 = fmaf(w.z, p[c + 2], a2);
      a3 = fmaf(w.w, p[c + 3], a3);
    }
    float h = fmaxf((a0 + a1) + (a2 + a3), 0.f);

#pragma unroll
    for (int c = 3; c < NCH; ++c) {
      float w2ck = W2[c * KH + k];       // s_load, 10.2KB -> K$-hot after 1st k
      dx[c - 3] = fmaf(w2ck, h, dx[c - 3]);
    }
  }

  // ---- stochastic fire mask (exact JAX partitionable threefry) ----
  const int gy = y0t + ty, gx = x0t + tx;
  float fire = fire_of(fk0, fk1, ((uint32_t)bb << 16) | ((uint32_t)gy << 8) | (uint32_t)gx);

  size_t base = (size_t)bb * (NCH * HH * WW) + (size_t)gy * WW + gx;
#pragma unroll
  for (int c = 0; c < NCH; ++c) {
    float v = p[c];
    if (c >= 3) v = v + dx[c - 3] * fire;
    xout[base + (size_t)c * (HH * WW)] = v;
  }
}

extern "C" void kernel_launch(void* const* d_in, const int* in_sizes, int n_in,
                              void* d_out, int out_size, void* d_ws, size_t ws_size,
                              hipStream_t stream) {
  const float* x  = (const float*)d_in[0];
  const float* W1 = (const float*)d_in[1];
  const float* b1 = (const float*)d_in[2];
  const float* W2 = (const float*)d_in[3];
  const int steps = 64;   // fixed by setup_inputs()

  float* bufWs  = (float*)d_ws;   // ping buffer, 41.94 MB
  float* bufOut = (float*)d_out;

  dim3 grid(WW / TSX, HH / TSY, 8);
  dim3 block(256);

  const float* src = x;
  for (int s = 0; s < steps; ++s) {
    uint32_t fk0, fk1;
    tf2x32(0u, 42u, 0u, (uint32_t)s, &fk0, &fk1);   // fold_in(key(42), s)
    float* dst = ((steps - 1 - s) & 1) ? bufWs : bufOut;  // final step -> d_out
    nca_step<<<grid, block, 0, stream>>>(src, dst, W1, b1, W2, fk0, fk1);
    src = dst;
  }
}

// Round 12
// 15087.125 us; speedup vs baseline: 1.0279x; 1.0279x over previous
//
#include <hip/hip_runtime.h>
#include <stdint.h>
#include <stddef.h>

#define HH 256
#define WW 256
#define NCH 20
#define KH 128
#define TSX 32
#define TSY 16
#define HALO_W 34
#define HALO_H 18
#define NTHR 512

// JAX threefry2x32 (20 rounds), exact.
__host__ __device__ inline void tf2x32(uint32_t k0, uint32_t k1,
                                       uint32_t x0, uint32_t x1,
                                       uint32_t* o0, uint32_t* o1) {
  uint32_t ks0 = k0, ks1 = k1, ks2 = k0 ^ k1 ^ 0x1BD11BDAu;
  x0 += ks0; x1 += ks1;
#define RND(r) { x0 += x1; x1 = (x1 << (r)) | (x1 >> (32 - (r))); x1 ^= x0; }
  RND(13) RND(15) RND(26) RND(6)   x0 += ks1; x1 += ks2 + 1u;
  RND(17) RND(29) RND(16) RND(24)  x0 += ks2; x1 += ks0 + 2u;
  RND(13) RND(15) RND(26) RND(6)   x0 += ks0; x1 += ks1 + 3u;
  RND(17) RND(29) RND(16) RND(24)  x0 += ks1; x1 += ks2 + 4u;
  RND(13) RND(15) RND(26) RND(6)   x0 += ks2; x1 += ks0 + 5u;
#undef RND
  *o0 = x0; *o1 = x1;
}

__device__ inline float fire_of(uint32_t fk0, uint32_t fk1, uint32_t f) {
  // JAX partitionable threefry: counts hi=0, lo=f; bits = o0 ^ o1
  uint32_t o0, o1;
  tf2x32(fk0, fk1, 0u, f, &o0, &o1);
  uint32_t bits = o0 ^ o1;
  float u = __uint_as_float((bits >> 9) | 0x3f800000u) - 1.0f;
  return (u < 0.5f) ? 1.0f : 0.0f;
}

// One NCA step, ONE pixel per thread, 512-thread blocks (32x16 tile).
// r10 lesson: 16x16 blocks -> 2 blocks/CU -> only 2 waves/SIMD -> latency-bound
// (42% FMA-issue efficiency). 512-thr keeps LDS/CU identical but doubles
// waves/SIMD to 4. Live set ~95 regs -> no spill (r10: VGPR=88).
// W1 in LDS (broadcast ds_read_b128); W2/b1 s_load (K$-hot).
__global__ __attribute__((amdgpu_flat_work_group_size(NTHR, NTHR), amdgpu_waves_per_eu(4, 4)))
void nca_step(
    const float* __restrict__ xin, float* __restrict__ xout,
    const float* __restrict__ W1, const float* __restrict__ b1,
    const float* __restrict__ W2, uint32_t fk0, uint32_t fk1)
{
  __shared__ float xs[NCH][HALO_H][HALO_W];  // 48.96 KB halo tile (32x16 px + 1 halo)
  __shared__ float w1s[KH * 60];             // 30.72 KB; row k at 240B offset (16B aligned)

  const int tid = threadIdx.x;
  const int bx = blockIdx.x, by = blockIdx.y, bb = blockIdx.z;
  const int x0t = bx * TSX, y0t = by * TSY;
  const float* xb = xin + (size_t)bb * (NCH * HH * WW);

  // ---- stage W1 into LDS (float4 coalesced; 1920 float4s) ----
  for (int i = tid; i < KH * 15; i += NTHR)
    ((float4*)w1s)[i] = ((const float4*)W1)[i];

  // ---- stage halo tile (reflect padding); rows are 136B -> decent lines ----
  for (int idx = tid; idx < NCH * HALO_H * HALO_W; idx += NTHR) {
    int c  = idx / (HALO_H * HALO_W);
    int r  = idx - c * (HALO_H * HALO_W);
    int ly = r / HALO_W;
    int lx = r - ly * HALO_W;
    int gy = y0t + ly - 1;
    int gx = x0t + lx - 1;
    gy = (gy < 0) ? -gy : gy;  gy = (gy >= HH) ? (2 * HH - 2 - gy) : gy;
    gx = (gx < 0) ? -gx : gx;  gx = (gx >= WW) ? (2 * WW - 2 - gx) : gx;
    xs[c][ly][lx] = xb[c * (HH * WW) + gy * WW + gx];
  }
  __syncthreads();

  const int tx = tid & 31, ty = tid >> 5;   // 32x16 pixel tile

  // ---- perceive: p[0..19]=center, p[20+2c]=sobel_x, p[21+2c]=sobel_y ----
  float p[60];
#pragma unroll
  for (int c = 0; c < NCH; ++c) {
    float a00 = xs[c][ty    ][tx], a01 = xs[c][ty    ][tx + 1], a02 = xs[c][ty    ][tx + 2];
    float a10 = xs[c][ty + 1][tx], a11 = xs[c][ty + 1][tx + 1], a12 = xs[c][ty + 1][tx + 2];
    float a20 = xs[c][ty + 2][tx], a21 = xs[c][ty + 2][tx + 1], a22 = xs[c][ty + 2][tx + 2];
    p[c] = a11;
    p[NCH + 2 * c    ] = ((a02 - a00) + 2.f * (a12 - a10) + (a22 - a20)) * 0.125f;
    p[NCH + 2 * c + 1] = ((a20 - a00) + 2.f * (a21 - a01) + (a22 - a02)) * 0.125f;
  }

  // dx only for mutable channels 3..19 (0..2 discarded by chan_mask)
  float dx[17];
#pragma unroll
  for (int c = 0; c < 17; ++c) dx[c] = 0.f;

  // ---- fused MLP over 128 hidden units ----
#pragma unroll 1
  for (int k = 0; k < KH; ++k) {
    const float bk = b1[k];              // s_load, 512B -> K$-hot
    float a0 = bk, a1 = 0.f, a2 = 0.f, a3 = 0.f;
#pragma unroll
    for (int c = 0; c < 60; c += 4) {
      float4 w = *(const float4*)&w1s[k * 60 + c];   // uniform broadcast ds_read_b128
      a0 = fmaf(w.x, p[c    ], a0);
      a1 = fmaf(w.y, p[c + 1], a1);
      a2 = fmaf(w.z, p[c + 2], a2);
      a3 = fmaf(w.w, p[c + 3], a3);
    }
    float h = fmaxf((a0 + a1) + (a2 + a3), 0.f);

#pragma unroll
    for (int c = 3; c < NCH; ++c) {
      float w2ck = W2[c * KH + k];       // s_load, 10.2KB -> K$-hot after 1st k
      dx[c - 3] = fmaf(w2ck, h, dx[c - 3]);
    }
  }

  // ---- stochastic fire mask (exact JAX partitionable threefry) ----
  const int gy = y0t + ty, gx = x0t + tx;
  float fire = fire_of(fk0, fk1, ((uint32_t)bb << 16) | ((uint32_t)gy << 8) | (uint32_t)gx);

  size_t base = (size_t)bb * (NCH * HH * WW) + (size_t)gy * WW + gx;
#pragma unroll
  for (int c = 0; c < NCH; ++c) {
    float v = p[c];
    if (c >= 3) v = v + dx[c - 3] * fire;
    xout[base + (size_t)c * (HH * WW)] = v;
  }
}

extern "C" void kernel_launch(void* const* d_in, const int* in_sizes, int n_in,
                              void* d_out, int out_size, void* d_ws, size_t ws_size,
                              hipStream_t stream) {
  const float* x  = (const float*)d_in[0];
  const float* W1 = (const float*)d_in[1];
  const float* b1 = (const float*)d_in[2];
  const float* W2 = (const float*)d_in[3];
  const int steps = 64;   // fixed by setup_inputs()

  float* bufWs  = (float*)d_ws;   // ping buffer, 41.94 MB
  float* bufOut = (float*)d_out;

  dim3 grid(WW / TSX, HH / TSY, 8);
  dim3 block(NTHR);

  const float* src = x;
  for (int s = 0; s < steps; ++s) {
    uint32_t fk0, fk1;
    tf2x32(0u, 42u, 0u, (uint32_t)s, &fk0, &fk1);   // fold_in(key(42), s)
    float* dst = ((steps - 1 - s) & 1) ? bufWs : bufOut;  // final step -> d_out
    nca_step<<<grid, block, 0, stream>>>(src, dst, W1, b1, W2, fk0, fk1);
    src = dst;
  }
}